// Round 14
// baseline (91.800 us; speedup 1.0000x reference)
//
#include <hip/hip_runtime.h>
#include <math.h>

// NSVQ: N=131072 rows, D=64, K=1024 codes (fp32).
// out (flat f32): [0,N*D) quantized; [N*D] perplexity; [N*D+1,+K) counts.
// ws layout:
//   [0,4096)         cn2k   f32[K]     2048*(||c||^2 + 512)
//   [4096,8192)      counts int[K]
//   [8192,532480)    best   uint[N]    bit31=flag, bits10..19=k2, bits0..9=k1
//   [532480,663552)  cbh    ushort[K*64] bf16 hi, MFMA-fragment order
//   [663552,794624)  cbl    ushort[K*64] bf16 lo, MFMA-fragment order
// fragment order: entry (16B) index = ct*128 + kk*64 + lg*16 + l15
//   holds code (ct*16+l15), dims [kk*32+lg*8, +8)  -> wave load is coalesced 1KB

#define NSVQ_D 64
#define ABN 256     // rows per argmin block (256 thr, 4 waves x 64 rows -> grid 512)
#define THR_Q 2u    // flag threshold in packed-float quanta (worst quantum 0.0625 raw)

typedef __attribute__((ext_vector_type(8))) short short8;
typedef __attribute__((ext_vector_type(4))) float f32x4;

__device__ __forceinline__ ushort bftrunc(float f) {
  return (ushort)(__float_as_uint(f) >> 16);
}
__device__ __forceinline__ float bf2f(ushort h) {
  return __uint_as_float(((uint)h) << 16);
}

// ---------------- prep: codebook norms + bf16 hi/lo split (fragment order) + zero counts ----------------
__global__ __launch_bounds__(256)
void nsvq_prep(const float* __restrict__ cb,
               ushort* __restrict__ cbh, ushort* __restrict__ cbl,
               float* __restrict__ cn2k, int* __restrict__ counts, int K) {
  if (blockIdx.x == 0) ((int4*)counts)[threadIdx.x] = make_int4(0, 0, 0, 0);
  int r = blockIdx.x * 256 + threadIdx.x;  // one code per thread
  if (r >= K) return;
  const float* row = cb + (long)r * NSVQ_D;
  float nrm = 0.f;
#pragma unroll
  for (int j = 0; j < 8; ++j) {            // dim block j = dims 8j..8j+7
    float4 v0 = *(const float4*)(row + j * 8);
    float4 v1 = *(const float4*)(row + j * 8 + 4);
    float f[8] = {v0.x, v0.y, v0.z, v0.w, v1.x, v1.y, v1.z, v1.w};
    ushort h[8], l[8];
#pragma unroll
    for (int e = 0; e < 8; ++e) {
      nrm = fmaf(f[e], f[e], nrm);
      ushort hb = bftrunc(f[e]);
      h[e] = hb;
      l[e] = bftrunc(f[e] - bf2f(hb));
    }
    // fragment-order entry: ct*128 + kk*64 + lg*16 + l15
    int blk = (r >> 4) * 128 + (j >> 2) * 64 + (j & 3) * 16 + (r & 15);
    *(uint4*)(cbh + blk * 8) = *(uint4*)h;
    *(uint4*)(cbl + blk * 8) = *(uint4*)l;
  }
  cn2k[r] = 2048.f * (nrm + 512.f);        // acc-init constant; scores in (0.9M, 1.5M) > 0
}

// ---------------- MFMA argmin: 4 waves x 64 rows, branchless 2-buffer pipeline ----------------
__global__ __launch_bounds__(256, 2)
void nsvq_argmin_mfma(const float* __restrict__ x,
                      const ushort* __restrict__ cbh,
                      const ushort* __restrict__ cbl,
                      const float* __restrict__ cn2k,
                      uint* __restrict__ best) {
  const int tid = threadIdx.x;
  const int lane = tid & 63;
  const int wid = tid >> 6;                // 0..3, each wave owns 64 rows
  const int l15 = lane & 15;
  const int lg = lane >> 4;                // 0..3
  const long brow = (long)blockIdx.x * ABN;
  const int wrow = wid * 64;

  // ---- A fragments (X rows scaled by -4096), bf16 hi/lo, register-resident ----
  short8 ah[4][2], al[4][2];
#pragma unroll
  for (int rt = 0; rt < 4; ++rt) {
#pragma unroll
    for (int kk = 0; kk < 2; ++kk) {
      const float* xr = x + (brow + wrow + rt * 16 + l15) * NSVQ_D + kk * 32 + lg * 8;
      float4 v0 = *(const float4*)xr;
      float4 v1 = *(const float4*)(xr + 4);
      float f[8] = {v0.x, v0.y, v0.z, v0.w, v1.x, v1.y, v1.z, v1.w};
      short8 h, lo;
#pragma unroll
      for (int j = 0; j < 8; ++j) {
        float fs = f[j] * -4096.f;         // exact pow2 scale; -2*2048 folded in
        ushort hb = bftrunc(fs);
        h[j] = (short)hb;
        lo[j] = (short)bftrunc(fs - bf2f(hb));
      }
      ah[rt][kk] = h;
      al[rt][kk] = lo;
    }
  }

  uint u1[16], u2[16];
#pragma unroll
  for (int i = 0; i < 16; ++i) { u1[i] = 0xFFFFFFFFu; u2[i] = 0xFFFFFFFFu; }

  const int lbase = lane * 8;              // ushort offset within a 64-entry group

  // branchless fragment load into named buffer regs
  auto LOAD = [&](short8& h0, short8& h1, short8& l0, short8& l1, float& cn, int c) {
    int nb = c * 1024 + lbase;
    h0 = *(const short8*)(cbh + nb);
    h1 = *(const short8*)(cbh + nb + 512);
    l0 = *(const short8*)(cbl + nb);
    l1 = *(const short8*)(cbl + nb + 512);
    cn = cn2k[(c << 4) + l15];
  };
  auto COMPUTE = [&](short8 h0, short8 h1, short8 l0, short8 l1, float cc, int ct) {
    const uint kidx = (uint)((ct << 4) + l15);
#pragma unroll
    for (int rt = 0; rt < 4; ++rt) {
      f32x4 a = {cc, cc, cc, cc};
      a = __builtin_amdgcn_mfma_f32_16x16x32_bf16(ah[rt][0], h0, a, 0, 0, 0);
      a = __builtin_amdgcn_mfma_f32_16x16x32_bf16(ah[rt][1], h1, a, 0, 0, 0);
      a = __builtin_amdgcn_mfma_f32_16x16x32_bf16(al[rt][0], h0, a, 0, 0, 0);
      a = __builtin_amdgcn_mfma_f32_16x16x32_bf16(al[rt][1], h1, a, 0, 0, 0);
      a = __builtin_amdgcn_mfma_f32_16x16x32_bf16(ah[rt][0], l0, a, 0, 0, 0);
      a = __builtin_amdgcn_mfma_f32_16x16x32_bf16(ah[rt][1], l1, a, 0, 0, 0);
#pragma unroll
      for (int j = 0; j < 4; ++j) {
        // positive float -> raw bits monotone; one v_and_or packs score|index
        uint m = (__float_as_uint(a[j]) & 0xFFFFFC00u) | kidx;
        int slot = rt * 4 + j;
        uint mm;  // u2' = median(u1, u2, m)  (valid since u1 <= u2 invariant)
        asm("v_med3_u32 %0, %1, %2, %3" : "=v"(mm)
            : "v"(u1[slot]), "v"(u2[slot]), "v"(m));
        u2[slot] = mm;
        u1[slot] = min(u1[slot], m);
      }
    }
  };

  short8 Ah0, Ah1, Al0, Al1, Bh0, Bh1, Bl0, Bl1;
  float cnA, cnB;
  LOAD(Ah0, Ah1, Al0, Al1, cnA, 0);
  LOAD(Bh0, Bh1, Bl0, Bl1, cnB, 1);

  for (int ct = 0; ct < 64; ct += 2) {
    COMPUTE(Ah0, Ah1, Al0, Al1, cnA, ct);
    int na = ct + 2 < 64 ? ct + 2 : 63;    // clamped, branchless (tail loads dead)
    LOAD(Ah0, Ah1, Al0, Al1, cnA, na);
    COMPUTE(Bh0, Bh1, Bl0, Bl1, cnB, ct + 1);
    int nb2 = ct + 3 < 64 ? ct + 3 : 63;
    LOAD(Bh0, Bh1, Bl0, Bl1, cnB, nb2);
  }

  // ---- cross-lane top-2 merge over the 16 code-lanes; write packed best ----
#pragma unroll
  for (int rt = 0; rt < 4; ++rt) {
#pragma unroll
    for (int j = 0; j < 4; ++j) {
      int slot = rt * 4 + j;
      uint a1 = u1[slot], a2 = u2[slot];
#pragma unroll
      for (int off = 1; off < 16; off <<= 1) {
        uint o1 = (uint)__shfl_xor((int)a1, off);
        uint o2 = (uint)__shfl_xor((int)a2, off);
        a2 = min(min(a2, o2), max(a1, o1));
        a1 = min(a1, o1);
      }
      if (l15 == 0) {
        uint fl = ((a2 >> 10) - (a1 >> 10) < THR_Q) ? 0x80000000u : 0u;
        best[brow + wrow + rt * 16 + lg * 4 + j] =
            fl | ((a2 & 1023u) << 10) | (a1 & 1023u);
      }
    }
  }
}

// ---------------- cleanup: per-thread top-2 exact check + counts histogram ----------------
__global__ __launch_bounds__(256)
void nsvq_cleanup(const float* __restrict__ x,
                  const float* __restrict__ cb,
                  const float* __restrict__ cn2k,
                  uint* __restrict__ best,
                  int* __restrict__ counts) {
  __shared__ int hist[1024];
#pragma unroll
  for (int i = threadIdx.x; i < 1024; i += 256) hist[i] = 0;
  __syncthreads();

  const long row = (long)blockIdx.x * 256 + threadIdx.x;
  uint p = best[row];
  uint k = p & 1023u;
  if (p & 0x80000000u) {
    uint k2 = (p >> 10) & 1023u;
    const float4* xr = (const float4*)(x + row * NSVQ_D);
    const float4* c1 = (const float4*)(cb + (long)k * NSVQ_D);
    const float4* c2 = (const float4*)(cb + (long)k2 * NSVQ_D);
    float d1 = 0.f, d2 = 0.f;
#pragma unroll
    for (int q = 0; q < 16; ++q) {
      float4 xv = xr[q], a = c1[q], b = c2[q];
      d1 = fmaf(xv.x, a.x, d1); d1 = fmaf(xv.y, a.y, d1);
      d1 = fmaf(xv.z, a.z, d1); d1 = fmaf(xv.w, a.w, d1);
      d2 = fmaf(xv.x, b.x, d2); d2 = fmaf(xv.y, b.y, d2);
      d2 = fmaf(xv.z, b.z, d2); d2 = fmaf(xv.w, b.w, d2);
    }
    float s1 = fmaf(-4096.f, d1, cn2k[k]);   // 2048*score, exact fp32 dot
    float s2 = fmaf(-4096.f, d2, cn2k[k2]);
    if (s2 < s1 || (s2 == s1 && k2 < k)) k = k2;
    best[row] = k;                            // clean entry for epilogue
  }
  atomicAdd(&hist[k], 1);
  __syncthreads();
  for (int i = threadIdx.x; i < 1024; i += 256) {
    int v = hist[i];
    if (v) atomicAdd(&counts[i], v);
  }
}

// ---------------- epilogue: noise-substitution quantization ----------------
__global__ __launch_bounds__(256)
void nsvq_epilogue_kernel(const float* __restrict__ x,
                          const float* __restrict__ cb,
                          const float* __restrict__ rv,
                          const uint* __restrict__ best,
                          float* __restrict__ out) {
  const int tid = threadIdx.x;
  const long row = (long)blockIdx.x * 16 + (tid >> 4);
  const int l = tid & 15;
  const int k = (int)(best[row] & 1023u);

  float4 xv = ((const float4*)(x + row * NSVQ_D))[l];
  float4 cv = ((const float4*)(cb + (long)k * NSVQ_D))[l];
  float4 rr = ((const float4*)(rv + row * NSVQ_D))[l];

  float dx = xv.x - cv.x, dy = xv.y - cv.y, dz = xv.z - cv.z, dw = xv.w - cv.w;
  float dres = dx * dx + dy * dy + dz * dz + dw * dw;
  float drnd = rr.x * rr.x + rr.y * rr.y + rr.z * rr.z + rr.w * rr.w;
#pragma unroll
  for (int off = 1; off < 16; off <<= 1) {
    dres += __shfl_xor(dres, off, 64);
    drnd += __shfl_xor(drnd, off, 64);
  }
  float scale = sqrtf(dres) / (sqrtf(drnd) + 1e-12f);

  float4 o;
  o.x = xv.x + scale * rr.x;
  o.y = xv.y + scale * rr.y;
  o.z = xv.z + scale * rr.z;
  o.w = xv.w + scale * rr.w;
  ((float4*)(out + row * NSVQ_D))[l] = o;
}

// ---------------- perplexity + counts output ----------------
__global__ void nsvq_perp_kernel(const int* __restrict__ counts,
                                 float* __restrict__ out_tail,  // [0]=perp, [1..K]=counts
                                 float invN, int K) {
  int t = threadIdx.x;
  float v = 0.f;
  if (t < K) {
    int c = counts[t];
    out_tail[1 + t] = (float)c;
    float p = (float)c * invN;
    v = p * logf(p + 1e-12f);
  }
#pragma unroll
  for (int off = 1; off < 64; off <<= 1) v += __shfl_xor(v, off, 64);
  __shared__ float red[16];
  int wid = t >> 6;
  if ((t & 63) == 0) red[wid] = v;
  __syncthreads();
  if (t == 0) {
    float s = 0.f;
    int nw = (blockDim.x + 63) / 64;
    for (int w = 0; w < nw; ++w) s += red[w];
    out_tail[0] = expf(-s);
  }
}

extern "C" void kernel_launch(void* const* d_in, const int* in_sizes, int n_in,
                              void* d_out, int out_size, void* d_ws, size_t ws_size,
                              hipStream_t stream) {
  const float* x  = (const float*)d_in[0];
  const float* cb = (const float*)d_in[1];
  const float* rv = (const float*)d_in[2];
  float* out = (float*)d_out;

  const int D = NSVQ_D;
  const int N = in_sizes[0] / D;  // 131072
  const int K = in_sizes[1] / D;  // 1024

  float*  cn2k   = (float*)d_ws;
  int*    counts = (int*)((char*)d_ws + 4096);
  uint*   best   = (uint*)((char*)d_ws + 8192);
  ushort* cbh    = (ushort*)((char*)d_ws + 532480);
  ushort* cbl    = (ushort*)((char*)d_ws + 663552);

  nsvq_prep<<<(K + 255) / 256, 256, 0, stream>>>(cb, cbh, cbl, cn2k, counts, K);
  nsvq_argmin_mfma<<<N / ABN, 256, 0, stream>>>(x, cbh, cbl, cn2k, best);
  nsvq_cleanup<<<N / 256, 256, 0, stream>>>(x, cb, cn2k, best, counts);
  nsvq_epilogue_kernel<<<N / 16, 256, 0, stream>>>(x, cb, rv, best, out);
  nsvq_perp_kernel<<<1, 1024, 0, stream>>>(counts, out + (size_t)N * D, 1.0f / (float)N, K);
}

// Round 15
// 76.088 us; speedup vs baseline: 1.2065x; 1.2065x over previous
//
#include <hip/hip_runtime.h>
#include <math.h>

// NSVQ: N=131072 rows, D=64, K=1024 codes (fp32).
// out (flat f32): [0,N*D) quantized; [N*D] perplexity; [N*D+1,+K) counts.
// ws layout:
//   [0,4096)         cn2k   f32[K]     2048*(||c||^2 + 512)
//   [4096,8192)      counts int[K]
//   [8192,532480)    best   uint[N]    bit31=flag, bits10..19=k2, bits0..9=k1
//   [532480,663552)  cbf    fp16[K*64] codebook, MFMA-fragment order
// fragment order: entry (16B) index = ct*128 + kk*64 + lg*16 + l15
//   holds code (ct*16+l15), dims [kk*32+lg*8, +8)  -> wave load is coalesced 1KB

#define NSVQ_D 64
#define ABN 256      // rows per argmin block (256 thr, 4 waves x 64 rows -> grid 512)
#define THR_Q 12u    // flag threshold in packed quanta (worst quantum 0.03125 raw @ e=19)
                     // certifies gap >= 0.375 raw > 2*fp16_err(0.12) + quantum

typedef __attribute__((ext_vector_type(8))) _Float16 half8;
typedef __attribute__((ext_vector_type(4))) float f32x4;

// ---------------- prep: codebook norms + fp16 fragment-order plane + zero counts ----------------
__global__ __launch_bounds__(256)
void nsvq_prep(const float* __restrict__ cb,
               ushort* __restrict__ cbf,
               float* __restrict__ cn2k, int* __restrict__ counts, int K) {
  if (blockIdx.x == 0) ((int4*)counts)[threadIdx.x] = make_int4(0, 0, 0, 0);
  int r = blockIdx.x * 256 + threadIdx.x;  // one code per thread
  if (r >= K) return;
  const float* row = cb + (long)r * NSVQ_D;
  float nrm = 0.f;
#pragma unroll
  for (int j = 0; j < 8; ++j) {            // dim block j = dims 8j..8j+7
    float4 v0 = *(const float4*)(row + j * 8);
    float4 v1 = *(const float4*)(row + j * 8 + 4);
    float f[8] = {v0.x, v0.y, v0.z, v0.w, v1.x, v1.y, v1.z, v1.w};
    half8 hv;
#pragma unroll
    for (int e = 0; e < 8; ++e) {
      nrm = fmaf(f[e], f[e], nrm);
      hv[e] = (_Float16)f[e];
    }
    // fragment-order entry: ct*128 + kk*64 + lg*16 + l15
    int blk = (r >> 4) * 128 + (j >> 2) * 64 + (j & 3) * 16 + (r & 15);
    *(half8*)(cbf + blk * 8) = hv;
  }
  cn2k[r] = 2048.f * (nrm + 512.f);        // acc-init constant; scores in (0.78M, 1.72M)
}

// ---------------- MFMA argmin: fp16 single-plane, 4 waves x 64 rows, 2-buffer pipeline ----------------
__global__ __launch_bounds__(256, 2)
void nsvq_argmin_mfma(const float* __restrict__ x,
                      const ushort* __restrict__ cbf,
                      const float* __restrict__ cn2k,
                      uint* __restrict__ best) {
  const int tid = threadIdx.x;
  const int lane = tid & 63;
  const int wid = tid >> 6;                // 0..3, each wave owns 64 rows
  const int l15 = lane & 15;
  const int lg = lane >> 4;                // 0..3
  const long brow = (long)blockIdx.x * ABN;
  const int wrow = wid * 64;

  // ---- A fragments (X rows scaled by -4096), fp16, register-resident ----
  half8 ax[4][2];
#pragma unroll
  for (int rt = 0; rt < 4; ++rt) {
#pragma unroll
    for (int kk = 0; kk < 2; ++kk) {
      const float* xr = x + (brow + wrow + rt * 16 + l15) * NSVQ_D + kk * 32 + lg * 8;
      float4 v0 = *(const float4*)xr;
      float4 v1 = *(const float4*)(xr + 4);
      float f[8] = {v0.x, v0.y, v0.z, v0.w, v1.x, v1.y, v1.z, v1.w};
      half8 h;
#pragma unroll
      for (int j = 0; j < 8; ++j) h[j] = (_Float16)(f[j] * -4096.f);
      ax[rt][kk] = h;
    }
  }

  uint u1[16], u2[16];
#pragma unroll
  for (int i = 0; i < 16; ++i) { u1[i] = 0xFFFFFFFFu; u2[i] = 0xFFFFFFFFu; }

  const int lbase = lane * 8;              // ushort offset within a 64-entry group

  auto LOAD = [&](half8& h0, half8& h1, float& cn, int c) {
    int nb = c * 1024 + lbase;
    h0 = *(const half8*)(cbf + nb);
    h1 = *(const half8*)(cbf + nb + 512);
    cn = cn2k[(c << 4) + l15];
  };
  auto COMPUTE = [&](half8 h0, half8 h1, float cc, int ct) {
    const uint kidx = (uint)((ct << 4) + l15);
#pragma unroll
    for (int rt = 0; rt < 4; ++rt) {
      f32x4 a = {cc, cc, cc, cc};
      a = __builtin_amdgcn_mfma_f32_16x16x32_f16(ax[rt][0], h0, a, 0, 0, 0);
      a = __builtin_amdgcn_mfma_f32_16x16x32_f16(ax[rt][1], h1, a, 0, 0, 0);
#pragma unroll
      for (int j = 0; j < 4; ++j) {
        // positive float -> raw bits monotone; one v_and_or packs score|index
        uint m = (__float_as_uint(a[j]) & 0xFFFFFC00u) | kidx;
        int slot = rt * 4 + j;
        uint mm;  // u2' = median(u1, u2, m)  (valid since u1 <= u2 invariant)
        asm("v_med3_u32 %0, %1, %2, %3" : "=v"(mm)
            : "v"(u1[slot]), "v"(u2[slot]), "v"(m));
        u2[slot] = mm;
        u1[slot] = min(u1[slot], m);
      }
    }
  };

  half8 Ah0, Ah1, Bh0, Bh1;
  float cnA, cnB;
  LOAD(Ah0, Ah1, cnA, 0);
  LOAD(Bh0, Bh1, cnB, 1);

  for (int ct = 0; ct < 64; ct += 2) {
    COMPUTE(Ah0, Ah1, cnA, ct);
    int na = ct + 2 < 64 ? ct + 2 : 63;    // clamped, branchless (tail loads dead)
    LOAD(Ah0, Ah1, cnA, na);
    COMPUTE(Bh0, Bh1, cnB, ct + 1);
    int nb2 = ct + 3 < 64 ? ct + 3 : 63;
    LOAD(Bh0, Bh1, cnB, nb2);
  }

  // ---- cross-lane top-2 merge over the 16 code-lanes; write packed best ----
#pragma unroll
  for (int rt = 0; rt < 4; ++rt) {
#pragma unroll
    for (int j = 0; j < 4; ++j) {
      int slot = rt * 4 + j;
      uint a1 = u1[slot], a2 = u2[slot];
#pragma unroll
      for (int off = 1; off < 16; off <<= 1) {
        uint o1 = (uint)__shfl_xor((int)a1, off);
        uint o2 = (uint)__shfl_xor((int)a2, off);
        a2 = min(min(a2, o2), max(a1, o1));
        a1 = min(a1, o1);
      }
      if (l15 == 0) {
        uint fl = ((a2 >> 10) - (a1 >> 10) < THR_Q) ? 0x80000000u : 0u;
        best[brow + wrow + rt * 16 + lg * 4 + j] =
            fl | ((a2 & 1023u) << 10) | (a1 & 1023u);
      }
    }
  }
}

// ---------------- cleanup: per-thread top-2 exact check + counts histogram ----------------
__global__ __launch_bounds__(256)
void nsvq_cleanup(const float* __restrict__ x,
                  const float* __restrict__ cb,
                  const float* __restrict__ cn2k,
                  uint* __restrict__ best,
                  int* __restrict__ counts) {
  __shared__ int hist[1024];
#pragma unroll
  for (int i = threadIdx.x; i < 1024; i += 256) hist[i] = 0;
  __syncthreads();

  const long row = (long)blockIdx.x * 256 + threadIdx.x;
  uint p = best[row];
  uint k = p & 1023u;
  if (p & 0x80000000u) {
    uint k2 = (p >> 10) & 1023u;
    const float4* xr = (const float4*)(x + row * NSVQ_D);
    const float4* c1 = (const float4*)(cb + (long)k * NSVQ_D);
    const float4* c2 = (const float4*)(cb + (long)k2 * NSVQ_D);
    float d1 = 0.f, d2 = 0.f;
#pragma unroll
    for (int q = 0; q < 16; ++q) {
      float4 xv = xr[q], a = c1[q], b = c2[q];
      d1 = fmaf(xv.x, a.x, d1); d1 = fmaf(xv.y, a.y, d1);
      d1 = fmaf(xv.z, a.z, d1); d1 = fmaf(xv.w, a.w, d1);
      d2 = fmaf(xv.x, b.x, d2); d2 = fmaf(xv.y, b.y, d2);
      d2 = fmaf(xv.z, b.z, d2); d2 = fmaf(xv.w, b.w, d2);
    }
    float s1 = fmaf(-4096.f, d1, cn2k[k]);   // 2048*score, exact fp32 dot
    float s2 = fmaf(-4096.f, d2, cn2k[k2]);
    if (s2 < s1 || (s2 == s1 && k2 < k)) k = k2;
    best[row] = k;                            // clean entry for epilogue
  }
  atomicAdd(&hist[k], 1);
  __syncthreads();
  for (int i = threadIdx.x; i < 1024; i += 256) {
    int v = hist[i];
    if (v) atomicAdd(&counts[i], v);
  }
}

// ---------------- epilogue: noise-substitution quantization ----------------
__global__ __launch_bounds__(256)
void nsvq_epilogue_kernel(const float* __restrict__ x,
                          const float* __restrict__ cb,
                          const float* __restrict__ rv,
                          const uint* __restrict__ best,
                          float* __restrict__ out) {
  const int tid = threadIdx.x;
  const long row = (long)blockIdx.x * 16 + (tid >> 4);
  const int l = tid & 15;
  const int k = (int)(best[row] & 1023u);

  float4 xv = ((const float4*)(x + row * NSVQ_D))[l];
  float4 cv = ((const float4*)(cb + (long)k * NSVQ_D))[l];
  float4 rr = ((const float4*)(rv + row * NSVQ_D))[l];

  float dx = xv.x - cv.x, dy = xv.y - cv.y, dz = xv.z - cv.z, dw = xv.w - cv.w;
  float dres = dx * dx + dy * dy + dz * dz + dw * dw;
  float drnd = rr.x * rr.x + rr.y * rr.y + rr.z * rr.z + rr.w * rr.w;
#pragma unroll
  for (int off = 1; off < 16; off <<= 1) {
    dres += __shfl_xor(dres, off, 64);
    drnd += __shfl_xor(drnd, off, 64);
  }
  float scale = sqrtf(dres) / (sqrtf(drnd) + 1e-12f);

  float4 o;
  o.x = xv.x + scale * rr.x;
  o.y = xv.y + scale * rr.y;
  o.z = xv.z + scale * rr.z;
  o.w = xv.w + scale * rr.w;
  ((float4*)(out + row * NSVQ_D))[l] = o;
}

// ---------------- perplexity + counts output ----------------
__global__ void nsvq_perp_kernel(const int* __restrict__ counts,
                                 float* __restrict__ out_tail,  // [0]=perp, [1..K]=counts
                                 float invN, int K) {
  int t = threadIdx.x;
  float v = 0.f;
  if (t < K) {
    int c = counts[t];
    out_tail[1 + t] = (float)c;
    float p = (float)c * invN;
    v = p * logf(p + 1e-12f);
  }
#pragma unroll
  for (int off = 1; off < 64; off <<= 1) v += __shfl_xor(v, off, 64);
  __shared__ float red[16];
  int wid = t >> 6;
  if ((t & 63) == 0) red[wid] = v;
  __syncthreads();
  if (t == 0) {
    float s = 0.f;
    int nw = (blockDim.x + 63) / 64;
    for (int w = 0; w < nw; ++w) s += red[w];
    out_tail[0] = expf(-s);
  }
}

extern "C" void kernel_launch(void* const* d_in, const int* in_sizes, int n_in,
                              void* d_out, int out_size, void* d_ws, size_t ws_size,
                              hipStream_t stream) {
  const float* x  = (const float*)d_in[0];
  const float* cb = (const float*)d_in[1];
  const float* rv = (const float*)d_in[2];
  float* out = (float*)d_out;

  const int D = NSVQ_D;
  const int N = in_sizes[0] / D;  // 131072
  const int K = in_sizes[1] / D;  // 1024

  float*  cn2k   = (float*)d_ws;
  int*    counts = (int*)((char*)d_ws + 4096);
  uint*   best   = (uint*)((char*)d_ws + 8192);
  ushort* cbf    = (ushort*)((char*)d_ws + 532480);

  nsvq_prep<<<(K + 255) / 256, 256, 0, stream>>>(cb, cbf, cn2k, counts, K);
  nsvq_argmin_mfma<<<N / ABN, 256, 0, stream>>>(x, cbf, cn2k, best);
  nsvq_cleanup<<<N / 256, 256, 0, stream>>>(x, cb, cn2k, best, counts);
  nsvq_epilogue_kernel<<<N / 16, 256, 0, stream>>>(x, cb, rv, best, out);
  nsvq_perp_kernel<<<1, 1024, 0, stream>>>(counts, out + (size_t)N * D, 1.0f / (float)N, K);
}

// Round 16
// 73.798 us; speedup vs baseline: 1.2439x; 1.0310x over previous
//
#include <hip/hip_runtime.h>
#include <math.h>

// NSVQ: N=131072 rows, D=64, K=1024 codes (fp32).
// out (flat f32): [0,N*D) quantized; [N*D] perplexity; [N*D+1,+K) counts.
// ws layout:
//   [0,4096)         cn2k   f32[K]     2048*(||c||^2 + 512)
//   [4096,8192)      counts int[K]
//   [8192,532480)    best   uint[N]    bit31=flag, bits10..19=k2, bits0..9=k1
//   [532480,663552)  cbf    fp16[K*64] codebook, MFMA-fragment order
// fragment order: entry (16B) index = ct*128 + kk*64 + lg*16 + l15
//   holds code (ct*16+l15), dims [kk*32+lg*8, +8)  -> wave load is coalesced 1KB

#define NSVQ_D 64
#define ABN 128      // rows per argmin block (256 thr, 4 waves x 32 rows -> grid 1024, 4 blk/CU)
#define THR_Q 12u    // flag threshold in packed quanta (worst quantum 0.03125 raw @ e=19)
                     // certifies gap >= 0.375 raw > 2*fp16_err(0.12) + quantum

typedef __attribute__((ext_vector_type(8))) _Float16 half8;
typedef __attribute__((ext_vector_type(4))) float f32x4;

// ---------------- prep: codebook norms + fp16 fragment-order plane + zero counts ----------------
__global__ __launch_bounds__(256)
void nsvq_prep(const float* __restrict__ cb,
               ushort* __restrict__ cbf,
               float* __restrict__ cn2k, int* __restrict__ counts, int K) {
  if (blockIdx.x == 0) ((int4*)counts)[threadIdx.x] = make_int4(0, 0, 0, 0);
  int r = blockIdx.x * 256 + threadIdx.x;  // one code per thread
  if (r >= K) return;
  const float* row = cb + (long)r * NSVQ_D;
  float nrm = 0.f;
#pragma unroll
  for (int j = 0; j < 8; ++j) {            // dim block j = dims 8j..8j+7
    float4 v0 = *(const float4*)(row + j * 8);
    float4 v1 = *(const float4*)(row + j * 8 + 4);
    float f[8] = {v0.x, v0.y, v0.z, v0.w, v1.x, v1.y, v1.z, v1.w};
    half8 hv;
#pragma unroll
    for (int e = 0; e < 8; ++e) {
      nrm = fmaf(f[e], f[e], nrm);
      hv[e] = (_Float16)f[e];
    }
    // fragment-order entry: ct*128 + kk*64 + lg*16 + l15
    int blk = (r >> 4) * 128 + (j >> 2) * 64 + (j & 3) * 16 + (r & 15);
    *(half8*)(cbf + blk * 8) = hv;
  }
  cn2k[r] = 2048.f * (nrm + 512.f);        // acc-init constant; scores in (0.78M, 1.72M)
}

// ---------------- MFMA argmin: fp16, 4 waves x 32 rows, 4 blocks/CU, 2-buffer pipeline ----------------
__global__ __launch_bounds__(256, 4)
void nsvq_argmin_mfma(const float* __restrict__ x,
                      const ushort* __restrict__ cbf,
                      const float* __restrict__ cn2k,
                      uint* __restrict__ best) {
  const int tid = threadIdx.x;
  const int lane = tid & 63;
  const int wid = tid >> 6;                // 0..3, each wave owns 32 rows
  const int l15 = lane & 15;
  const int lg = lane >> 4;                // 0..3
  const long brow = (long)blockIdx.x * ABN;
  const int wrow = wid * 32;

  // ---- A fragments (X rows scaled by -4096), fp16, register-resident ----
  half8 ax[2][2];
#pragma unroll
  for (int rt = 0; rt < 2; ++rt) {
#pragma unroll
    for (int kk = 0; kk < 2; ++kk) {
      const float* xr = x + (brow + wrow + rt * 16 + l15) * NSVQ_D + kk * 32 + lg * 8;
      float4 v0 = *(const float4*)xr;
      float4 v1 = *(const float4*)(xr + 4);
      float f[8] = {v0.x, v0.y, v0.z, v0.w, v1.x, v1.y, v1.z, v1.w};
      half8 h;
#pragma unroll
      for (int j = 0; j < 8; ++j) h[j] = (_Float16)(f[j] * -4096.f);
      ax[rt][kk] = h;
    }
  }

  uint u1[8], u2[8];
#pragma unroll
  for (int i = 0; i < 8; ++i) { u1[i] = 0xFFFFFFFFu; u2[i] = 0xFFFFFFFFu; }

  const int lbase = lane * 8;              // ushort offset within a 64-entry group

  auto LOAD = [&](half8& h0, half8& h1, float& cn, int c) {
    int nb = c * 1024 + lbase;
    h0 = *(const half8*)(cbf + nb);
    h1 = *(const half8*)(cbf + nb + 512);
    cn = cn2k[(c << 4) + l15];
  };
  auto COMPUTE = [&](half8 h0, half8 h1, float cc, int ct) {
    const uint kidx = (uint)((ct << 4) + l15);
#pragma unroll
    for (int rt = 0; rt < 2; ++rt) {
      f32x4 a = {cc, cc, cc, cc};
      a = __builtin_amdgcn_mfma_f32_16x16x32_f16(ax[rt][0], h0, a, 0, 0, 0);
      a = __builtin_amdgcn_mfma_f32_16x16x32_f16(ax[rt][1], h1, a, 0, 0, 0);
#pragma unroll
      for (int j = 0; j < 4; ++j) {
        // positive float -> raw bits monotone; one v_and_or packs score|index
        uint m = (__float_as_uint(a[j]) & 0xFFFFFC00u) | kidx;
        int slot = rt * 4 + j;
        uint mm;  // u2' = median(u1, u2, m)  (valid since u1 <= u2 invariant)
        asm("v_med3_u32 %0, %1, %2, %3" : "=v"(mm)
            : "v"(u1[slot]), "v"(u2[slot]), "v"(m));
        u2[slot] = mm;
        u1[slot] = min(u1[slot], m);
      }
    }
  };

  half8 Ah0, Ah1, Bh0, Bh1;
  float cnA, cnB;
  LOAD(Ah0, Ah1, cnA, 0);
  LOAD(Bh0, Bh1, cnB, 1);

  for (int ct = 0; ct < 64; ct += 2) {
    COMPUTE(Ah0, Ah1, cnA, ct);
    int na = ct + 2 < 64 ? ct + 2 : 63;    // clamped, branchless (tail loads dead)
    LOAD(Ah0, Ah1, cnA, na);
    COMPUTE(Bh0, Bh1, cnB, ct + 1);
    int nb2 = ct + 3 < 64 ? ct + 3 : 63;
    LOAD(Bh0, Bh1, cnB, nb2);
  }

  // ---- cross-lane top-2 merge over the 16 code-lanes; write packed best ----
#pragma unroll
  for (int rt = 0; rt < 2; ++rt) {
#pragma unroll
    for (int j = 0; j < 4; ++j) {
      int slot = rt * 4 + j;
      uint a1 = u1[slot], a2 = u2[slot];
#pragma unroll
      for (int off = 1; off < 16; off <<= 1) {
        uint o1 = (uint)__shfl_xor((int)a1, off);
        uint o2 = (uint)__shfl_xor((int)a2, off);
        a2 = min(min(a2, o2), max(a1, o1));
        a1 = min(a1, o1);
      }
      if (l15 == 0) {
        uint fl = ((a2 >> 10) - (a1 >> 10) < THR_Q) ? 0x80000000u : 0u;
        best[brow + wrow + rt * 16 + lg * 4 + j] =
            fl | ((a2 & 1023u) << 10) | (a1 & 1023u);
      }
    }
  }
}

// ---------------- cleanup: per-thread top-2 exact check + counts histogram ----------------
__global__ __launch_bounds__(256)
void nsvq_cleanup(const float* __restrict__ x,
                  const float* __restrict__ cb,
                  const float* __restrict__ cn2k,
                  uint* __restrict__ best,
                  int* __restrict__ counts) {
  __shared__ int hist[1024];
#pragma unroll
  for (int i = threadIdx.x; i < 1024; i += 256) hist[i] = 0;
  __syncthreads();

  const long row = (long)blockIdx.x * 256 + threadIdx.x;
  uint p = best[row];
  uint k = p & 1023u;
  if (p & 0x80000000u) {
    uint k2 = (p >> 10) & 1023u;
    const float4* xr = (const float4*)(x + row * NSVQ_D);
    const float4* c1 = (const float4*)(cb + (long)k * NSVQ_D);
    const float4* c2 = (const float4*)(cb + (long)k2 * NSVQ_D);
    float d1 = 0.f, d2 = 0.f;
#pragma unroll
    for (int q = 0; q < 16; ++q) {
      float4 xv = xr[q], a = c1[q], b = c2[q];
      d1 = fmaf(xv.x, a.x, d1); d1 = fmaf(xv.y, a.y, d1);
      d1 = fmaf(xv.z, a.z, d1); d1 = fmaf(xv.w, a.w, d1);
      d2 = fmaf(xv.x, b.x, d2); d2 = fmaf(xv.y, b.y, d2);
      d2 = fmaf(xv.z, b.z, d2); d2 = fmaf(xv.w, b.w, d2);
    }
    float s1 = fmaf(-4096.f, d1, cn2k[k]);   // 2048*score, exact fp32 dot
    float s2 = fmaf(-4096.f, d2, cn2k[k2]);
    if (s2 < s1 || (s2 == s1 && k2 < k)) k = k2;
    best[row] = k;                            // clean entry for epilogue
  }
  atomicAdd(&hist[k], 1);
  __syncthreads();
  for (int i = threadIdx.x; i < 1024; i += 256) {
    int v = hist[i];
    if (v) atomicAdd(&counts[i], v);
  }
}

// ---------------- epilogue: noise-substitution quantization ----------------
__global__ __launch_bounds__(256)
void nsvq_epilogue_kernel(const float* __restrict__ x,
                          const float* __restrict__ cb,
                          const float* __restrict__ rv,
                          const uint* __restrict__ best,
                          float* __restrict__ out) {
  const int tid = threadIdx.x;
  const long row = (long)blockIdx.x * 16 + (tid >> 4);
  const int l = tid & 15;
  const int k = (int)(best[row] & 1023u);

  float4 xv = ((const float4*)(x + row * NSVQ_D))[l];
  float4 cv = ((const float4*)(cb + (long)k * NSVQ_D))[l];
  float4 rr = ((const float4*)(rv + row * NSVQ_D))[l];

  float dx = xv.x - cv.x, dy = xv.y - cv.y, dz = xv.z - cv.z, dw = xv.w - cv.w;
  float dres = dx * dx + dy * dy + dz * dz + dw * dw;
  float drnd = rr.x * rr.x + rr.y * rr.y + rr.z * rr.z + rr.w * rr.w;
#pragma unroll
  for (int off = 1; off < 16; off <<= 1) {
    dres += __shfl_xor(dres, off, 64);
    drnd += __shfl_xor(drnd, off, 64);
  }
  float scale = sqrtf(dres) / (sqrtf(drnd) + 1e-12f);

  float4 o;
  o.x = xv.x + scale * rr.x;
  o.y = xv.y + scale * rr.y;
  o.z = xv.z + scale * rr.z;
  o.w = xv.w + scale * rr.w;
  ((float4*)(out + row * NSVQ_D))[l] = o;
}

// ---------------- perplexity + counts output ----------------
__global__ void nsvq_perp_kernel(const int* __restrict__ counts,
                                 float* __restrict__ out_tail,  // [0]=perp, [1..K]=counts
                                 float invN, int K) {
  int t = threadIdx.x;
  float v = 0.f;
  if (t < K) {
    int c = counts[t];
    out_tail[1 + t] = (float)c;
    float p = (float)c * invN;
    v = p * logf(p + 1e-12f);
  }
#pragma unroll
  for (int off = 1; off < 64; off <<= 1) v += __shfl_xor(v, off, 64);
  __shared__ float red[16];
  int wid = t >> 6;
  if ((t & 63) == 0) red[wid] = v;
  __syncthreads();
  if (t == 0) {
    float s = 0.f;
    int nw = (blockDim.x + 63) / 64;
    for (int w = 0; w < nw; ++w) s += red[w];
    out_tail[0] = expf(-s);
  }
}

extern "C" void kernel_launch(void* const* d_in, const int* in_sizes, int n_in,
                              void* d_out, int out_size, void* d_ws, size_t ws_size,
                              hipStream_t stream) {
  const float* x  = (const float*)d_in[0];
  const float* cb = (const float*)d_in[1];
  const float* rv = (const float*)d_in[2];
  float* out = (float*)d_out;

  const int D = NSVQ_D;
  const int N = in_sizes[0] / D;  // 131072
  const int K = in_sizes[1] / D;  // 1024

  float*  cn2k   = (float*)d_ws;
  int*    counts = (int*)((char*)d_ws + 4096);
  uint*   best   = (uint*)((char*)d_ws + 8192);
  ushort* cbf    = (ushort*)((char*)d_ws + 532480);

  nsvq_prep<<<(K + 255) / 256, 256, 0, stream>>>(cb, cbf, cn2k, counts, K);
  nsvq_argmin_mfma<<<N / ABN, 256, 0, stream>>>(x, cbf, cn2k, best);
  nsvq_cleanup<<<N / 256, 256, 0, stream>>>(x, cb, cn2k, best, counts);
  nsvq_epilogue_kernel<<<N / 16, 256, 0, stream>>>(x, cb, rv, best, out);
  nsvq_perp_kernel<<<1, 1024, 0, stream>>>(counts, out + (size_t)N * D, 1.0f / (float)N, K);
}